// Round 4
// baseline (724.947 us; speedup 1.0000x reference)
//
#include <hip/hip_runtime.h>
#include <math.h>

// Problem constants (reference: x[8,2048,1024] f32, W[1024,64] f32)
#define BB 8
#define NN 2048
#define DD 1024
#define EE 64
#define CAP 64
#define NTOK (BB * NN)          // 16384
#define OUT_T_FLOATS 67108864   // 8*2048*64*64 per tensor
#define OUT_T_F4     16777216   // float4 count per tensor

// Workspace layout (bytes):
//   recs      float4[NTOK]   @ 0        {g1n, g2n, bits(i1), bits(i2 | flag<<8)}
//   frecs     float4[NTOK]   @ 262144   {g1|0, g2|0, bits(e1*64+p1 | -1), bits(e2*64+p2 | -1)}
//   dens      float[256*64]  @ 524288   per-gating-block density partials
//   lossp     float[8]       @ 589824   per-batch loss partials

// ---------------------------------------------------------------------------
// Kernel G (v4 body, DIAGNOSTIC rep x3): the exact 609-us-baseline gating
// kernel, executed 3x inside one dispatch (idempotent: reads only x,W;
// recs/dens rewritten identically each rep).
//   dur_us ~= 609 + 2*G_warm  -> direct per-kernel attribution.
//   If 3*G > ~340us the dispatch enters the top-5 and we get G's own
//   VALUBusy / FETCH_SIZE / OccupancyPercent to pick the fix branch.
// ---------------------------------------------------------------------------
__global__ __launch_bounds__(1024, 4) void gating_kernel(
    const float* __restrict__ x, const float* __restrict__ W,
    float4* __restrict__ recs, float* __restrict__ dens)
{
    __shared__ float red[4][64][65];    // [kslice][expert][token+pad] 65 KB
    __shared__ float dred[4][64];

    const int tid  = threadIdx.x;
    const int lane = tid & 63;                                   // token-in-block
    const int wave = __builtin_amdgcn_readfirstlane(tid >> 6);
    const int ks   = wave & 3;                                   // k-slice (256 k)
    const int eq   = wave >> 2;                                  // expert quarter
    const int tok  = blockIdx.x * 64 + lane;

    const float4* xq = (const float4*)(x + (size_t)tok * DD + ks * 256);
    const float*  wq = W + (size_t)(ks * 256) * EE + eq * 16;    // wave-uniform

#pragma unroll 1
    for (int rep = 0; rep < 3; ++rep) {

        float acc[16];
#pragma unroll
        for (int j = 0; j < 16; ++j) acc[j] = 0.f;

#pragma unroll 2
        for (int c = 0; c < 64; ++c) {           // 64 float4 of x = 256 k
            const float4 xv = xq[c];
            const float xs[4] = {xv.x, xv.y, xv.z, xv.w};
#pragma unroll
            for (int kk = 0; kk < 4; ++kk) {
                const float4* wr = (const float4*)(wq + (size_t)(c * 4 + kk) * EE);
                const float4 w0 = wr[0], w1 = wr[1], w2 = wr[2], w3 = wr[3];
                acc[ 0] = fmaf(xs[kk], w0.x, acc[ 0]);
                acc[ 1] = fmaf(xs[kk], w0.y, acc[ 1]);
                acc[ 2] = fmaf(xs[kk], w0.z, acc[ 2]);
                acc[ 3] = fmaf(xs[kk], w0.w, acc[ 3]);
                acc[ 4] = fmaf(xs[kk], w1.x, acc[ 4]);
                acc[ 5] = fmaf(xs[kk], w1.y, acc[ 5]);
                acc[ 6] = fmaf(xs[kk], w1.z, acc[ 6]);
                acc[ 7] = fmaf(xs[kk], w1.w, acc[ 7]);
                acc[ 8] = fmaf(xs[kk], w2.x, acc[ 8]);
                acc[ 9] = fmaf(xs[kk], w2.y, acc[ 9]);
                acc[10] = fmaf(xs[kk], w2.z, acc[10]);
                acc[11] = fmaf(xs[kk], w2.w, acc[11]);
                acc[12] = fmaf(xs[kk], w3.x, acc[12]);
                acc[13] = fmaf(xs[kk], w3.y, acc[13]);
                acc[14] = fmaf(xs[kk], w3.z, acc[14]);
                acc[15] = fmaf(xs[kk], w3.w, acc[15]);
            }
        }

        // ---- one-shot cross-slice reduce via LDS
#pragma unroll
        for (int j = 0; j < 16; ++j)
            red[ks][eq * 16 + j][lane] = acc[j];     // lane stride 1: conflict-free
        __syncthreads();

        // ---- epilogue: waves 0-3, wave w handles tokens [16w,16w+16); lane = expert
        if (wave < 4) {
            const int t0 = wave * 16;
            float densacc = 0.f;
#pragma unroll 1
            for (int ti = 0; ti < 16; ++ti) {
                const int t = t0 + ti;
                const float lv = ((red[0][lane][t] + red[1][lane][t])
                                + red[2][lane][t]) + red[3][lane][t];  // stride 65: free

                // argmax: value desc, index asc on ties (matches jnp.argmax)
                float v = lv; int bi = lane;
#pragma unroll
                for (int off = 32; off; off >>= 1) {
                    float ov = __shfl_xor(v, off);
                    int   oi = __shfl_xor(bi, off);
                    if (ov > v || (ov == v && oi < bi)) { v = ov; bi = oi; }
                }
                const float m1 = v; const int i1 = bi;
                float v2 = (lane == i1) ? -INFINITY : lv; int b2 = lane;
#pragma unroll
                for (int off = 32; off; off >>= 1) {
                    float ov = __shfl_xor(v2, off);
                    int   oi = __shfl_xor(b2, off);
                    if (ov > v2 || (ov == v2 && oi < b2)) { v2 = ov; b2 = oi; }
                }
                const float m2 = v2; const int i2 = b2;

                float ex = expf(lv - m1);
                float Z = ex;
#pragma unroll
                for (int off = 32; off; off >>= 1) Z += __shfl_xor(Z, off);
                float g1 = 1.0f / Z;               // p[i1]
                float g2 = expf(m2 - m1) * g1;     // p[i2]
                float den = g1 + g2 + 1e-9f;
                float g1n = g1 / den;
                float g2n = g2 / den;
                int flag = (g2n > 0.2f) ? 1 : 0;   // threshold on NORMALIZED gate_2

                densacc += ex * g1;                // p_t[lane] for density proxy

                if (lane == 0)
                    recs[blockIdx.x * 64 + t] =
                        make_float4(g1n, g2n, __int_as_float(i1),
                                    __int_as_float(i2 | (flag << 8)));
            }
            dred[wave][lane] = densacc;
        }
        __syncthreads();
        if (tid < 64) {
            float s = dred[0][tid] + dred[1][tid] + dred[2][tid] + dred[3][tid];
            dens[blockIdx.x * 64 + tid] = s;       // per-block partial, no atomics
        }
        __syncthreads();   // red[] reuse fence for next rep
    }
}

// ---------------------------------------------------------------------------
// Kernel S: ballot-based parallel rank for position-in-expert.
// 1 block/batch, 1024 threads = 16 waves (unchanged, 609-baseline verbatim).
// ---------------------------------------------------------------------------
__global__ __launch_bounds__(1024) void scan_kernel(
    const float4* __restrict__ recs, const float* __restrict__ dens,
    float4* __restrict__ frecs, float* __restrict__ lossp)
{
    const int b = blockIdx.x;
    __shared__ int hist1[32][64], pre1[32][64];
    __shared__ int hist2[32][64], pre2[32][64];
    __shared__ int base2[64];
    __shared__ float dsum[64];

    const int tid = threadIdx.x;
    const int lane = tid & 63;
    const int wave = tid >> 6;

    float4 r[2];
    int e1[2], e2[2], fl[2], rank1[2], rank2[2];
    const unsigned long long below = (1ull << lane) - 1ull;

#pragma unroll
    for (int u = 0; u < 2; ++u) {
        const int g = 2 * wave + u;
        const int tok = g * 64 + lane;
        float4 rr = recs[b * NN + tok];
        r[u] = rr;
        e1[u] = __float_as_int(rr.z);
        int i2f = __float_as_int(rr.w);
        e2[u] = i2f & 63;
        fl[u] = i2f >> 8;

        unsigned long long m = ~0ull, mv = ~0ull;
#pragma unroll
        for (int bit = 0; bit < 6; ++bit) {
            unsigned long long vt = __ballot((e1[u] >> bit) & 1);
            m  &= ((e1[u] >> bit) & 1) ? vt : ~vt;
            mv &= ((lane  >> bit) & 1) ? vt : ~vt;
        }
        rank1[u] = __popcll(m & below);
        hist1[g][lane] = __popcll(mv);

        unsigned long long fv = __ballot(fl[u]);
        m = fv; mv = fv;
#pragma unroll
        for (int bit = 0; bit < 6; ++bit) {
            unsigned long long vt = __ballot((e2[u] >> bit) & 1);
            m  &= ((e2[u] >> bit) & 1) ? vt : ~vt;
            mv &= ((lane  >> bit) & 1) ? vt : ~vt;
        }
        rank2[u] = __popcll(m & below);
        hist2[g][lane] = __popcll(mv);
    }

    if (wave == 0) {  // density sums: 32 gating blocks per batch
        float s = 0.f;
        for (int k = 0; k < 32; ++k) s += dens[(b * 32 + k) * 64 + lane];
        dsum[lane] = s;
    }
    __syncthreads();

    if (wave == 0) {  // cross-group exclusive prefix, lane = expert
        int run = 0;
#pragma unroll
        for (int g = 0; g < 32; ++g) { pre1[g][lane] = run; run += hist1[g][lane]; }
        base2[lane] = run < CAP ? run : CAP;     // mask_1_count = min(count, cap)
        int run2 = 0;
#pragma unroll
        for (int g = 0; g < 32; ++g) { pre2[g][lane] = run2; run2 += hist2[g][lane]; }
        float v = dsum[lane] * (float)run;       // UNCAPPED count for loss
#pragma unroll
        for (int off = 32; off; off >>= 1) v += __shfl_xor(v, off);
        if (lane == 0) lossp[b] = v;
    }
    __syncthreads();

#pragma unroll
    for (int u = 0; u < 2; ++u) {
        const int g = 2 * wave + u;
        const int tok = g * 64 + lane;
        int p1 = rank1[u] + pre1[g][e1[u]];
        int k1 = p1 < CAP;
        int p2 = rank2[u] + pre2[g][e2[u]] + base2[e2[u]];
        int k2 = fl[u] && (p2 < CAP);
        float4 fr;
        fr.x = k1 ? r[u].x : 0.f;
        fr.y = k2 ? r[u].y : 0.f;
        fr.z = __int_as_float(k1 ? (e1[u] * CAP + p1) : -1);
        fr.w = __int_as_float(k2 ? (e2[u] * CAP + p2) : -1);
        frecs[b * NN + tok] = fr;
    }
}

// ---------------------------------------------------------------------------
// Kernel F (v1, 609-baseline verbatim): one float4 of each tensor per
// thread, 65536 one-shot blocks, plain stores.
// ---------------------------------------------------------------------------
__global__ __launch_bounds__(256) void fill_kernel(
    const float4* __restrict__ frecs, const float* __restrict__ lossp,
    float* __restrict__ out)
{
    const int tid = blockIdx.x * 256 + threadIdx.x;   // 0 .. 16777215
    const int token = tid >> 10;
    const int e  = (tid >> 4) & 63;
    const int c4 = tid & 15;
    float4 r = frecs[token];   // broadcast across 1024 threads -> L1 hit

    float cx = 0.f, cy = 0.f, cz = 0.f, cw = 0.f;
    float dx = 0.f, dy = 0.f, dz = 0.f, dw = 0.f;

    int p1 = __float_as_int(r.z);
    if (p1 >= 0 && (p1 >> 6) == e && ((p1 >> 2) & 15) == c4) {
        int cc = p1 & 3;
        if      (cc == 0) { cx = r.x; dx = 1.f; }
        else if (cc == 1) { cy = r.x; dy = 1.f; }
        else if (cc == 2) { cz = r.x; dz = 1.f; }
        else              { cw = r.x; dw = 1.f; }
    }
    int p2 = __float_as_int(r.w);
    if (p2 >= 0 && (p2 >> 6) == e && ((p2 >> 2) & 15) == c4) {
        int cc = p2 & 3;
        if      (cc == 0) { cx = r.y; dx = 1.f; }
        else if (cc == 1) { cy = r.y; dy = 1.f; }
        else if (cc == 2) { cz = r.y; dz = 1.f; }
        else              { cw = r.y; dw = 1.f; }
    }

    float4* o4 = (float4*)out;
    o4[tid]             = make_float4(dx, dy, dz, dw);   // dispatch
    o4[tid + OUT_T_F4]  = make_float4(cx, cy, cz, cw);   // combine

    if (tid == 0) {
        float s = 0.f;
        for (int k = 0; k < 8; ++k) s += lossp[k];
        // loss = sum_b lossp[b] * e^2 / (b*e*n^2) = s / 524288
        out[2 * (size_t)OUT_T_FLOATS] = s * (1.0f / 524288.0f);
    }
}

extern "C" void kernel_launch(void* const* d_in, const int* in_sizes, int n_in,
                              void* d_out, int out_size, void* d_ws, size_t ws_size,
                              hipStream_t stream)
{
    const float* x = (const float*)d_in[0];
    const float* W = (const float*)d_in[1];
    float* out = (float*)d_out;
    char* ws = (char*)d_ws;

    float4* recs  = (float4*)(ws);
    float4* frecs = (float4*)(ws + 262144);
    float*  dens  = (float*)(ws + 524288);
    float*  lossp = (float*)(ws + 589824);

    gating_kernel<<<256, 1024, 0, stream>>>(x, W, recs, dens);   // rep x3 inside
    scan_kernel<<<8, 1024, 0, stream>>>(recs, dens, frecs, lossp);
    fill_kernel<<<65536, 256, 0, stream>>>(frecs, lossp, out);
}

// Round 5
// 631.816 us; speedup vs baseline: 1.1474x; 1.1474x over previous
//
#include <hip/hip_runtime.h>
#include <math.h>

// Problem constants (reference: x[8,2048,1024] f32, W[1024,64] f32)
#define BB 8
#define NN 2048
#define DD 1024
#define EE 64
#define CAP 64
#define NTOK (BB * NN)          // 16384
#define OUT_T_FLOATS 67108864   // 8*2048*64*64 per tensor
#define OUT_T_F4     16777216   // float4 count per tensor

// Session ledger (measured):
//   dur = ~340us harness poison-drain + G + S + F
//   G(v4) = 58us   [rep-x3, round 4]
//   S + F = 209us  [two independent rounds]
//   This round: S x3 -> dur = 609 + 2*S. F = 209 - S by subtraction.

// Workspace layout (bytes):
//   recs      float4[NTOK]   @ 0        {g1n, g2n, bits(i1), bits(i2 | flag<<8)}
//   frecs     float4[NTOK]   @ 262144   {g1|0, g2|0, bits(e1*64+p1 | -1), bits(e2*64+p2 | -1)}
//   dens      float[256*64]  @ 524288   per-gating-block density partials
//   lossp     float[8]       @ 589824   per-batch loss partials

// ---------------------------------------------------------------------------
// Kernel G (v4, 609-baseline verbatim, NO reps): 256 blocks x 1024 threads;
// block owns 64 tokens (lane = token). 16 waves = 4 k-slices x 4
// expert-quarters -> acc[16]/thread. Measured: 58us.
// ---------------------------------------------------------------------------
__global__ __launch_bounds__(1024, 4) void gating_kernel(
    const float* __restrict__ x, const float* __restrict__ W,
    float4* __restrict__ recs, float* __restrict__ dens)
{
    __shared__ float red[4][64][65];    // [kslice][expert][token+pad] 65 KB
    __shared__ float dred[4][64];

    const int tid  = threadIdx.x;
    const int lane = tid & 63;                                   // token-in-block
    const int wave = __builtin_amdgcn_readfirstlane(tid >> 6);
    const int ks   = wave & 3;                                   // k-slice (256 k)
    const int eq   = wave >> 2;                                  // expert quarter
    const int tok  = blockIdx.x * 64 + lane;

    float acc[16];
#pragma unroll
    for (int j = 0; j < 16; ++j) acc[j] = 0.f;

    const float4* xq = (const float4*)(x + (size_t)tok * DD + ks * 256);
    const float*  wq = W + (size_t)(ks * 256) * EE + eq * 16;    // wave-uniform

#pragma unroll 2
    for (int c = 0; c < 64; ++c) {           // 64 float4 of x = 256 k
        const float4 xv = xq[c];
        const float xs[4] = {xv.x, xv.y, xv.z, xv.w};
#pragma unroll
        for (int kk = 0; kk < 4; ++kk) {
            const float4* wr = (const float4*)(wq + (size_t)(c * 4 + kk) * EE);
            const float4 w0 = wr[0], w1 = wr[1], w2 = wr[2], w3 = wr[3];
            acc[ 0] = fmaf(xs[kk], w0.x, acc[ 0]);
            acc[ 1] = fmaf(xs[kk], w0.y, acc[ 1]);
            acc[ 2] = fmaf(xs[kk], w0.z, acc[ 2]);
            acc[ 3] = fmaf(xs[kk], w0.w, acc[ 3]);
            acc[ 4] = fmaf(xs[kk], w1.x, acc[ 4]);
            acc[ 5] = fmaf(xs[kk], w1.y, acc[ 5]);
            acc[ 6] = fmaf(xs[kk], w1.z, acc[ 6]);
            acc[ 7] = fmaf(xs[kk], w1.w, acc[ 7]);
            acc[ 8] = fmaf(xs[kk], w2.x, acc[ 8]);
            acc[ 9] = fmaf(xs[kk], w2.y, acc[ 9]);
            acc[10] = fmaf(xs[kk], w2.z, acc[10]);
            acc[11] = fmaf(xs[kk], w2.w, acc[11]);
            acc[12] = fmaf(xs[kk], w3.x, acc[12]);
            acc[13] = fmaf(xs[kk], w3.y, acc[13]);
            acc[14] = fmaf(xs[kk], w3.z, acc[14]);
            acc[15] = fmaf(xs[kk], w3.w, acc[15]);
        }
    }

    // ---- one-shot cross-slice reduce via LDS
#pragma unroll
    for (int j = 0; j < 16; ++j)
        red[ks][eq * 16 + j][lane] = acc[j];     // lane stride 1: conflict-free
    __syncthreads();

    // ---- epilogue: waves 0-3, wave w handles tokens [16w,16w+16); lane = expert
    if (wave < 4) {
        const int t0 = wave * 16;
        float densacc = 0.f;
#pragma unroll 1
        for (int ti = 0; ti < 16; ++ti) {
            const int t = t0 + ti;
            const float lv = ((red[0][lane][t] + red[1][lane][t])
                            + red[2][lane][t]) + red[3][lane][t];  // stride 65: free

            // argmax: value desc, index asc on ties (matches jnp.argmax)
            float v = lv; int bi = lane;
#pragma unroll
            for (int off = 32; off; off >>= 1) {
                float ov = __shfl_xor(v, off);
                int   oi = __shfl_xor(bi, off);
                if (ov > v || (ov == v && oi < bi)) { v = ov; bi = oi; }
            }
            const float m1 = v; const int i1 = bi;
            float v2 = (lane == i1) ? -INFINITY : lv; int b2 = lane;
#pragma unroll
            for (int off = 32; off; off >>= 1) {
                float ov = __shfl_xor(v2, off);
                int   oi = __shfl_xor(b2, off);
                if (ov > v2 || (ov == v2 && oi < b2)) { v2 = ov; b2 = oi; }
            }
            const float m2 = v2; const int i2 = b2;

            float ex = expf(lv - m1);
            float Z = ex;
#pragma unroll
            for (int off = 32; off; off >>= 1) Z += __shfl_xor(Z, off);
            float g1 = 1.0f / Z;               // p[i1]
            float g2 = expf(m2 - m1) * g1;     // p[i2]
            float den = g1 + g2 + 1e-9f;
            float g1n = g1 / den;
            float g2n = g2 / den;
            int flag = (g2n > 0.2f) ? 1 : 0;   // threshold on NORMALIZED gate_2

            densacc += ex * g1;                // p_t[lane] for density proxy

            if (lane == 0)
                recs[blockIdx.x * 64 + t] =
                    make_float4(g1n, g2n, __int_as_float(i1),
                                __int_as_float(i2 | (flag << 8)));
        }
        dred[wave][lane] = densacc;
    }
    __syncthreads();
    if (tid < 64) {
        float s = dred[0][tid] + dred[1][tid] + dred[2][tid] + dred[3][tid];
        dens[blockIdx.x * 64 + tid] = s;       // per-block partial, no atomics
    }
}

// ---------------------------------------------------------------------------
// Kernel S (DIAGNOSTIC rep x3): idempotent (reads recs/dens, rewrites
// frecs/lossp with identical values; all LDS fully rewritten per rep).
// dur_us ~= 609 + 2*S  -> exact S; F = 209 - S by subtraction.
// asm memory fence per rep stops dead-store folding of repeated frecs writes.
// ---------------------------------------------------------------------------
__global__ __launch_bounds__(1024) void scan_kernel(
    const float4* __restrict__ recs, const float* __restrict__ dens,
    float4* __restrict__ frecs, float* __restrict__ lossp)
{
    const int b = blockIdx.x;
    __shared__ int hist1[32][64], pre1[32][64];
    __shared__ int hist2[32][64], pre2[32][64];
    __shared__ int base2[64];
    __shared__ float dsum[64];

    const int tid = threadIdx.x;
    const int lane = tid & 63;
    const int wave = tid >> 6;
    const unsigned long long below = (1ull << lane) - 1ull;

#pragma unroll 1
    for (int rep = 0; rep < 3; ++rep) {

        float4 r[2];
        int e1[2], e2[2], fl[2], rank1[2], rank2[2];

#pragma unroll
        for (int u = 0; u < 2; ++u) {
            const int g = 2 * wave + u;
            const int tok = g * 64 + lane;
            float4 rr = recs[b * NN + tok];
            r[u] = rr;
            e1[u] = __float_as_int(rr.z);
            int i2f = __float_as_int(rr.w);
            e2[u] = i2f & 63;
            fl[u] = i2f >> 8;

            unsigned long long m = ~0ull, mv = ~0ull;
#pragma unroll
            for (int bit = 0; bit < 6; ++bit) {
                unsigned long long vt = __ballot((e1[u] >> bit) & 1);
                m  &= ((e1[u] >> bit) & 1) ? vt : ~vt;
                mv &= ((lane  >> bit) & 1) ? vt : ~vt;
            }
            rank1[u] = __popcll(m & below);
            hist1[g][lane] = __popcll(mv);

            unsigned long long fv = __ballot(fl[u]);
            m = fv; mv = fv;
#pragma unroll
            for (int bit = 0; bit < 6; ++bit) {
                unsigned long long vt = __ballot((e2[u] >> bit) & 1);
                m  &= ((e2[u] >> bit) & 1) ? vt : ~vt;
                mv &= ((lane  >> bit) & 1) ? vt : ~vt;
            }
            rank2[u] = __popcll(m & below);
            hist2[g][lane] = __popcll(mv);
        }

        if (wave == 0) {  // density sums: 32 gating blocks per batch
            float s = 0.f;
            for (int k = 0; k < 32; ++k) s += dens[(b * 32 + k) * 64 + lane];
            dsum[lane] = s;
        }
        __syncthreads();

        if (wave == 0) {  // cross-group exclusive prefix, lane = expert
            int run = 0;
#pragma unroll
            for (int g = 0; g < 32; ++g) { pre1[g][lane] = run; run += hist1[g][lane]; }
            base2[lane] = run < CAP ? run : CAP;   // mask_1_count = min(count, cap)
            int run2 = 0;
#pragma unroll
            for (int g = 0; g < 32; ++g) { pre2[g][lane] = run2; run2 += hist2[g][lane]; }
            float v = dsum[lane] * (float)run;     // UNCAPPED count for loss
#pragma unroll
            for (int off = 32; off; off >>= 1) v += __shfl_xor(v, off);
            if (lane == 0) lossp[b] = v;
        }
        __syncthreads();

#pragma unroll
        for (int u = 0; u < 2; ++u) {
            const int g = 2 * wave + u;
            const int tok = g * 64 + lane;
            int p1 = rank1[u] + pre1[g][e1[u]];
            int k1 = p1 < CAP;
            int p2 = rank2[u] + pre2[g][e2[u]] + base2[e2[u]];
            int k2 = fl[u] && (p2 < CAP);
            float4 fr;
            fr.x = k1 ? r[u].x : 0.f;
            fr.y = k2 ? r[u].y : 0.f;
            fr.z = __int_as_float(k1 ? (e1[u] * CAP + p1) : -1);
            fr.w = __int_as_float(k2 ? (e2[u] * CAP + p2) : -1);
            frecs[b * NN + tok] = fr;
        }

        __syncthreads();                       // LDS reuse fence for next rep
        asm volatile("" ::: "memory");         // keep per-rep global stores live
    }
}

// ---------------------------------------------------------------------------
// Kernel F (v1, 609-baseline verbatim): one float4 of each tensor per
// thread, 65536 one-shot blocks, plain stores.
// ---------------------------------------------------------------------------
__global__ __launch_bounds__(256) void fill_kernel(
    const float4* __restrict__ frecs, const float* __restrict__ lossp,
    float* __restrict__ out)
{
    const int tid = blockIdx.x * 256 + threadIdx.x;   // 0 .. 16777215
    const int token = tid >> 10;
    const int e  = (tid >> 4) & 63;
    const int c4 = tid & 15;
    float4 r = frecs[token];   // broadcast across 1024 threads -> L1 hit

    float cx = 0.f, cy = 0.f, cz = 0.f, cw = 0.f;
    float dx = 0.f, dy = 0.f, dz = 0.f, dw = 0.f;

    int p1 = __float_as_int(r.z);
    if (p1 >= 0 && (p1 >> 6) == e && ((p1 >> 2) & 15) == c4) {
        int cc = p1 & 3;
        if      (cc == 0) { cx = r.x; dx = 1.f; }
        else if (cc == 1) { cy = r.x; dy = 1.f; }
        else if (cc == 2) { cz = r.x; dz = 1.f; }
        else              { cw = r.x; dw = 1.f; }
    }
    int p2 = __float_as_int(r.w);
    if (p2 >= 0 && (p2 >> 6) == e && ((p2 >> 2) & 15) == c4) {
        int cc = p2 & 3;
        if      (cc == 0) { cx = r.y; dx = 1.f; }
        else if (cc == 1) { cy = r.y; dy = 1.f; }
        else if (cc == 2) { cz = r.y; dz = 1.f; }
        else              { cw = r.y; dw = 1.f; }
    }

    float4* o4 = (float4*)out;
    o4[tid]             = make_float4(dx, dy, dz, dw);   // dispatch
    o4[tid + OUT_T_F4]  = make_float4(cx, cy, cz, cw);   // combine

    if (tid == 0) {
        float s = 0.f;
        for (int k = 0; k < 8; ++k) s += lossp[k];
        // loss = sum_b lossp[b] * e^2 / (b*e*n^2) = s / 524288
        out[2 * (size_t)OUT_T_FLOATS] = s * (1.0f / 524288.0f);
    }
}

extern "C" void kernel_launch(void* const* d_in, const int* in_sizes, int n_in,
                              void* d_out, int out_size, void* d_ws, size_t ws_size,
                              hipStream_t stream)
{
    const float* x = (const float*)d_in[0];
    const float* W = (const float*)d_in[1];
    float* out = (float*)d_out;
    char* ws = (char*)d_ws;

    float4* recs  = (float4*)(ws);
    float4* frecs = (float4*)(ws + 262144);
    float*  dens  = (float*)(ws + 524288);
    float*  lossp = (float*)(ws + 589824);

    gating_kernel<<<256, 1024, 0, stream>>>(x, W, recs, dens);
    scan_kernel<<<8, 1024, 0, stream>>>(recs, dens, frecs, lossp);   // rep x3 inside
    fill_kernel<<<65536, 256, 0, stream>>>(frecs, lossp, out);
}

// Round 6
// 550.953 us; speedup vs baseline: 1.3158x; 1.1468x over previous
//
#include <hip/hip_runtime.h>
#include <math.h>

// Problem constants (reference: x[8,2048,1024] f32, W[1024,64] f32)
#define BB 8
#define NN 2048
#define DD 1024
#define EE 64
#define CAP 64
#define NTOK (BB * NN)          // 16384
#define OUT_T_FLOATS 67108864   // 8*2048*64*64 per tensor

// Session ledger (measured):
//   dur = ~340us harness poison-drain + G + S + F
//   G(v4) = 58us  [rep-x3, round 4]
//   S     = 11us  [rep-x3, round 5]
//   F(dense v1) = ~200us vs ~88us floor  -> replaced this round by
//   hipMemsetAsync (runtime fill hits 6.3 TB/s) + sparse scatter (<=2
//   nonzeros/token/tensor, ~49K dword stores total).

// Workspace layout (bytes):
//   recs      float4[NTOK]   @ 0        {g1n, g2n, bits(i1), bits(i2 | flag<<8)}
//   frecs     float4[NTOK]   @ 262144   {g1|0, g2|0, bits(e1*64+p1 | -1), bits(e2*64+p2 | -1)}
//   dens      float[256*64]  @ 524288   per-gating-block density partials
//   lossp     float[8]       @ 589824   per-batch loss partials

// ---------------------------------------------------------------------------
// Kernel G (v4, 609-baseline verbatim): 256 blocks x 1024 threads; block owns
// 64 tokens (lane = token). 16 waves = 4 k-slices x 4 expert-quarters ->
// acc[16]/thread. Measured: 58us.
// ---------------------------------------------------------------------------
__global__ __launch_bounds__(1024, 4) void gating_kernel(
    const float* __restrict__ x, const float* __restrict__ W,
    float4* __restrict__ recs, float* __restrict__ dens)
{
    __shared__ float red[4][64][65];    // [kslice][expert][token+pad] 65 KB
    __shared__ float dred[4][64];

    const int tid  = threadIdx.x;
    const int lane = tid & 63;                                   // token-in-block
    const int wave = __builtin_amdgcn_readfirstlane(tid >> 6);
    const int ks   = wave & 3;                                   // k-slice (256 k)
    const int eq   = wave >> 2;                                  // expert quarter
    const int tok  = blockIdx.x * 64 + lane;

    float acc[16];
#pragma unroll
    for (int j = 0; j < 16; ++j) acc[j] = 0.f;

    const float4* xq = (const float4*)(x + (size_t)tok * DD + ks * 256);
    const float*  wq = W + (size_t)(ks * 256) * EE + eq * 16;    // wave-uniform

#pragma unroll 2
    for (int c = 0; c < 64; ++c) {           // 64 float4 of x = 256 k
        const float4 xv = xq[c];
        const float xs[4] = {xv.x, xv.y, xv.z, xv.w};
#pragma unroll
        for (int kk = 0; kk < 4; ++kk) {
            const float4* wr = (const float4*)(wq + (size_t)(c * 4 + kk) * EE);
            const float4 w0 = wr[0], w1 = wr[1], w2 = wr[2], w3 = wr[3];
            acc[ 0] = fmaf(xs[kk], w0.x, acc[ 0]);
            acc[ 1] = fmaf(xs[kk], w0.y, acc[ 1]);
            acc[ 2] = fmaf(xs[kk], w0.z, acc[ 2]);
            acc[ 3] = fmaf(xs[kk], w0.w, acc[ 3]);
            acc[ 4] = fmaf(xs[kk], w1.x, acc[ 4]);
            acc[ 5] = fmaf(xs[kk], w1.y, acc[ 5]);
            acc[ 6] = fmaf(xs[kk], w1.z, acc[ 6]);
            acc[ 7] = fmaf(xs[kk], w1.w, acc[ 7]);
            acc[ 8] = fmaf(xs[kk], w2.x, acc[ 8]);
            acc[ 9] = fmaf(xs[kk], w2.y, acc[ 9]);
            acc[10] = fmaf(xs[kk], w2.z, acc[10]);
            acc[11] = fmaf(xs[kk], w2.w, acc[11]);
            acc[12] = fmaf(xs[kk], w3.x, acc[12]);
            acc[13] = fmaf(xs[kk], w3.y, acc[13]);
            acc[14] = fmaf(xs[kk], w3.z, acc[14]);
            acc[15] = fmaf(xs[kk], w3.w, acc[15]);
        }
    }

    // ---- one-shot cross-slice reduce via LDS
#pragma unroll
    for (int j = 0; j < 16; ++j)
        red[ks][eq * 16 + j][lane] = acc[j];     // lane stride 1: conflict-free
    __syncthreads();

    // ---- epilogue: waves 0-3, wave w handles tokens [16w,16w+16); lane = expert
    if (wave < 4) {
        const int t0 = wave * 16;
        float densacc = 0.f;
#pragma unroll 1
        for (int ti = 0; ti < 16; ++ti) {
            const int t = t0 + ti;
            const float lv = ((red[0][lane][t] + red[1][lane][t])
                            + red[2][lane][t]) + red[3][lane][t];  // stride 65: free

            // argmax: value desc, index asc on ties (matches jnp.argmax)
            float v = lv; int bi = lane;
#pragma unroll
            for (int off = 32; off; off >>= 1) {
                float ov = __shfl_xor(v, off);
                int   oi = __shfl_xor(bi, off);
                if (ov > v || (ov == v && oi < bi)) { v = ov; bi = oi; }
            }
            const float m1 = v; const int i1 = bi;
            float v2 = (lane == i1) ? -INFINITY : lv; int b2 = lane;
#pragma unroll
            for (int off = 32; off; off >>= 1) {
                float ov = __shfl_xor(v2, off);
                int   oi = __shfl_xor(b2, off);
                if (ov > v2 || (ov == v2 && oi < b2)) { v2 = ov; b2 = oi; }
            }
            const float m2 = v2; const int i2 = b2;

            float ex = expf(lv - m1);
            float Z = ex;
#pragma unroll
            for (int off = 32; off; off >>= 1) Z += __shfl_xor(Z, off);
            float g1 = 1.0f / Z;               // p[i1]
            float g2 = expf(m2 - m1) * g1;     // p[i2]
            float den = g1 + g2 + 1e-9f;
            float g1n = g1 / den;
            float g2n = g2 / den;
            int flag = (g2n > 0.2f) ? 1 : 0;   // threshold on NORMALIZED gate_2

            densacc += ex * g1;                // p_t[lane] for density proxy

            if (lane == 0)
                recs[blockIdx.x * 64 + t] =
                    make_float4(g1n, g2n, __int_as_float(i1),
                                __int_as_float(i2 | (flag << 8)));
        }
        dred[wave][lane] = densacc;
    }
    __syncthreads();
    if (tid < 64) {
        float s = dred[0][tid] + dred[1][tid] + dred[2][tid] + dred[3][tid];
        dens[blockIdx.x * 64 + tid] = s;       // per-block partial, no atomics
    }
}

// ---------------------------------------------------------------------------
// Kernel S (609-baseline verbatim, single-shot): ballot-based parallel rank
// for position-in-expert. 1 block/batch, 1024 threads. Measured: 11us.
// ---------------------------------------------------------------------------
__global__ __launch_bounds__(1024) void scan_kernel(
    const float4* __restrict__ recs, const float* __restrict__ dens,
    float4* __restrict__ frecs, float* __restrict__ lossp)
{
    const int b = blockIdx.x;
    __shared__ int hist1[32][64], pre1[32][64];
    __shared__ int hist2[32][64], pre2[32][64];
    __shared__ int base2[64];
    __shared__ float dsum[64];

    const int tid = threadIdx.x;
    const int lane = tid & 63;
    const int wave = tid >> 6;

    float4 r[2];
    int e1[2], e2[2], fl[2], rank1[2], rank2[2];
    const unsigned long long below = (1ull << lane) - 1ull;

#pragma unroll
    for (int u = 0; u < 2; ++u) {
        const int g = 2 * wave + u;
        const int tok = g * 64 + lane;
        float4 rr = recs[b * NN + tok];
        r[u] = rr;
        e1[u] = __float_as_int(rr.z);
        int i2f = __float_as_int(rr.w);
        e2[u] = i2f & 63;
        fl[u] = i2f >> 8;

        unsigned long long m = ~0ull, mv = ~0ull;
#pragma unroll
        for (int bit = 0; bit < 6; ++bit) {
            unsigned long long vt = __ballot((e1[u] >> bit) & 1);
            m  &= ((e1[u] >> bit) & 1) ? vt : ~vt;
            mv &= ((lane  >> bit) & 1) ? vt : ~vt;
        }
        rank1[u] = __popcll(m & below);
        hist1[g][lane] = __popcll(mv);

        unsigned long long fv = __ballot(fl[u]);
        m = fv; mv = fv;
#pragma unroll
        for (int bit = 0; bit < 6; ++bit) {
            unsigned long long vt = __ballot((e2[u] >> bit) & 1);
            m  &= ((e2[u] >> bit) & 1) ? vt : ~vt;
            mv &= ((lane  >> bit) & 1) ? vt : ~vt;
        }
        rank2[u] = __popcll(m & below);
        hist2[g][lane] = __popcll(mv);
    }

    if (wave == 0) {  // density sums: 32 gating blocks per batch
        float s = 0.f;
        for (int k = 0; k < 32; ++k) s += dens[(b * 32 + k) * 64 + lane];
        dsum[lane] = s;
    }
    __syncthreads();

    if (wave == 0) {  // cross-group exclusive prefix, lane = expert
        int run = 0;
#pragma unroll
        for (int g = 0; g < 32; ++g) { pre1[g][lane] = run; run += hist1[g][lane]; }
        base2[lane] = run < CAP ? run : CAP;     // mask_1_count = min(count, cap)
        int run2 = 0;
#pragma unroll
        for (int g = 0; g < 32; ++g) { pre2[g][lane] = run2; run2 += hist2[g][lane]; }
        float v = dsum[lane] * (float)run;       // UNCAPPED count for loss
#pragma unroll
        for (int off = 32; off; off >>= 1) v += __shfl_xor(v, off);
        if (lane == 0) lossp[b] = v;
    }
    __syncthreads();

#pragma unroll
    for (int u = 0; u < 2; ++u) {
        const int g = 2 * wave + u;
        const int tok = g * 64 + lane;
        int p1 = rank1[u] + pre1[g][e1[u]];
        int k1 = p1 < CAP;
        int p2 = rank2[u] + pre2[g][e2[u]] + base2[e2[u]];
        int k2 = fl[u] && (p2 < CAP);
        float4 fr;
        fr.x = k1 ? r[u].x : 0.f;
        fr.y = k2 ? r[u].y : 0.f;
        fr.z = __int_as_float(k1 ? (e1[u] * CAP + p1) : -1);
        fr.w = __int_as_float(k2 ? (e2[u] * CAP + p2) : -1);
        frecs[b * NN + tok] = fr;
    }
}

// ---------------------------------------------------------------------------
// Kernel F (v3, SPARSE): out has been zeroed by hipMemsetAsync (runtime fill
// runs at ~6.3 TB/s, vs our dense kernel's measured ~2.7). Only the <=2
// nonzero (expert,pos) slots per token per tensor need stores: ~49K dword
// scatter total. One thread per token, 64 blocks x 256.
//   frecs.z/.w already encode e*CAP+pos in [0,4096) or -1.
//   dispatch[token*4096 + ep] = 1.0 ; combine[token*4096 + ep] = gate.
// ---------------------------------------------------------------------------
__global__ __launch_bounds__(256) void sparse_fill_kernel(
    const float4* __restrict__ frecs, const float* __restrict__ lossp,
    float* __restrict__ out)
{
    const int token = blockIdx.x * 256 + threadIdx.x;   // 0 .. 16383
    const float4 r = frecs[token];
    float* __restrict__ dsp = out;
    float* __restrict__ cmb = out + (size_t)OUT_T_FLOATS;
    const size_t base = (size_t)token * (EE * CAP);

    const int p1 = __float_as_int(r.z);
    if (p1 >= 0) {
        dsp[base + p1] = 1.0f;
        cmb[base + p1] = r.x;
    }
    const int p2 = __float_as_int(r.w);
    if (p2 >= 0) {
        dsp[base + p2] = 1.0f;
        cmb[base + p2] = r.y;
    }

    if (token == 0) {
        float s = 0.f;
        for (int k = 0; k < 8; ++k) s += lossp[k];
        // loss = sum_b lossp[b] * e^2 / (b*e*n^2) = s / 524288
        out[2 * (size_t)OUT_T_FLOATS] = s * (1.0f / 524288.0f);
    }
}

extern "C" void kernel_launch(void* const* d_in, const int* in_sizes, int n_in,
                              void* d_out, int out_size, void* d_ws, size_t ws_size,
                              hipStream_t stream)
{
    const float* x = (const float*)d_in[0];
    const float* W = (const float*)d_in[1];
    float* out = (float*)d_out;
    char* ws = (char*)d_ws;

    float4* recs  = (float4*)(ws);
    float4* frecs = (float4*)(ws + 262144);
    float*  dens  = (float*)(ws + 524288);
    float*  lossp = (float*)(ws + 589824);

    // zero the whole output (both tensors + loss) via the runtime's
    // optimized fill (~6.3 TB/s measured on this very buffer); stream-ordered
    // and graph-capturable.
    hipMemsetAsync(d_out, 0, (size_t)out_size, stream);

    gating_kernel<<<256, 1024, 0, stream>>>(x, W, recs, dens);
    scan_kernel<<<8, 1024, 0, stream>>>(recs, dens, frecs, lossp);
    sparse_fill_kernel<<<NTOK / 256, 256, 0, stream>>>(frecs, lossp, out);
}